// Round 6
// baseline (198.104 us; speedup 1.0000x reference)
//
#include <hip/hip_runtime.h>
#include <stdint.h>

#define N_EMBD 1024
#define NHEAD  16
#define HDIM   64
#define BATCH  8
#define SEQ    1024
#define MROWS  (BATCH*SEQ)   // 8192

typedef __bf16 bf16x8 __attribute__((ext_vector_type(8)));
typedef float  f32x4  __attribute__((ext_vector_type(4)));

__device__ inline unsigned short f2bf(float f) {
  uint32_t u = __float_as_uint(f);
  u += 0x7FFFu + ((u >> 16) & 1u);   // RNE; inputs are finite
  return (unsigned short)(u >> 16);
}

__device__ inline f32x4 mfma_bf16(bf16x8 a, bf16x8 b, f32x4 c) {
  return __builtin_amdgcn_mfma_f32_16x16x32_bf16(a, b, c, 0, 0, 0);
}

__device__ inline void gload_lds16(const unsigned short* g, unsigned short* l) {
  __builtin_amdgcn_global_load_lds(
      (const __attribute__((address_space(1))) void*)g,
      (__attribute__((address_space(3))) void*)l,
      16, 0, 0);
}

#define DSB __builtin_amdgcn_sched_barrier(0)
#define BARRIER __builtin_amdgcn_s_barrier()

// ---------------- cast f32 -> bf16 (vectorized) ----------------
__global__ __launch_bounds__(256) void cast_f32_bf16(
    const float* __restrict__ in, unsigned short* __restrict__ out, int n) {
  int i = (blockIdx.x * 256 + threadIdx.x) * 4;
  if (i >= n) return;
  float4 v = *(const float4*)(in + i);
  ushort4 o;
  o.x = f2bf(v.x); o.y = f2bf(v.y); o.z = f2bf(v.z); o.w = f2bf(v.w);
  *(ushort4*)(out + i) = o;
}

// ---------------- transpose + cast: in [K][N] f32 -> out [N][K] bf16 ----------------
__global__ __launch_bounds__(256) void transpose_cast(
    const float* __restrict__ in, unsigned short* __restrict__ out, int K, int N) {
  __shared__ unsigned short tile[64 * 72];
  int k0 = blockIdx.y * 64, n0 = blockIdx.x * 64;
  int t = threadIdx.x;
  {
    int col = (t & 15) * 4;
#pragma unroll
    for (int it = 0; it < 4; ++it) {
      int row = (t >> 4) + it * 16;
      float4 v = *(const float4*)(in + (size_t)(k0 + row) * N + n0 + col);
      ushort4 o;
      o.x = f2bf(v.x); o.y = f2bf(v.y); o.z = f2bf(v.z); o.w = f2bf(v.w);
      *(ushort4*)&tile[row * 72 + col] = o;
    }
  }
  __syncthreads();
  {
    int kcol = (t & 7) * 8;
#pragma unroll
    for (int it = 0; it < 2; ++it) {
      int nrow = (t >> 3) + it * 32;
      alignas(16) unsigned short tmp[8];
#pragma unroll
      for (int j = 0; j < 8; ++j) tmp[j] = tile[(kcol + j) * 72 + nrow];
      *(uint4*)(out + (size_t)(n0 + nrow) * K + k0 + kcol) = *(const uint4*)tmp;
    }
  }
}

// ---------------- GEMM v3: 8-phase 256x256 template (T1+T2+T3+T4+T5) ----------------
// BM=BN=256, BK=64, 8 waves (2M x 4N), per-wave 128x64 = acc[8][4].
// LDS 128 KB: Al/Bl [2][256*64] bf16, XOR-swizzled via pre-swizzled global source.
// 8 phases / 2 K-tiles; 2 gloads/phase; vmcnt(2) at phases 0 and 4 only.
// K=1024 fixed -> 16 K-tiles -> 8 main iterations.

#define G8_STAGE(bufi, c, koBytes)                                              \
  gload_lds16((const unsigned short*)(Agp + (size_t)(c) * 64 * 2048 + (koBytes)),\
              &Al[bufi][tid * 8 + (c) * 4096]);                                  \
  gload_lds16((const unsigned short*)(Bgp + (size_t)(c) * 64 * 2048 + (koBytes)),\
              &Bl[bufi][tid * 8 + (c) * 4096]);

#define G8_LDA(bufc, MH, COLK)                                                  \
  _Pragma("unroll") for (int mm = 0; mm < 4; ++mm)                              \
      avreg[mm] = *(const bf16x8*)((const char*)&Al[bufc][0] + arow +           \
                                   (MH) * 8192 + mm * 2048 + (COLK));
#define G8_LDB(bufc, COLK)                                                      \
  _Pragma("unroll") for (int nn = 0; nn < 4; ++nn)                              \
      bvreg[nn] = *(const bf16x8*)((const char*)&Bl[bufc][0] + brow +           \
                                   nn * 2048 + (COLK));
#define G8_MFMA(MH)                                                             \
  __builtin_amdgcn_s_setprio(1);                                                \
  _Pragma("unroll") for (int nn = 0; nn < 4; ++nn)                              \
      _Pragma("unroll") for (int mm = 0; mm < 4; ++mm)                          \
          acc[(MH) * 4 + mm][nn] =                                              \
              mfma_bf16(avreg[mm], bvreg[nn], acc[(MH) * 4 + mm][nn]);          \
  __builtin_amdgcn_s_setprio(0);
#define LGKM0 asm volatile("s_waitcnt lgkmcnt(0)" ::: "memory"); DSB;
#define VMC(n) asm volatile("s_waitcnt vmcnt(" #n ")" ::: "memory");

#define GEMM8_CORE(A_, Bt_, NBX_)                                               \
  __shared__ unsigned short Al[2][256 * 64];                                    \
  __shared__ unsigned short Bl[2][256 * 64];                                    \
  const int tid = threadIdx.x;                                                  \
  const int l = tid & 63, w = tid >> 6;                                         \
  const int wr = w >> 2, wc = w & 3;                                            \
  const int g = l >> 4, fr = l & 15;                                            \
  const int nwg = NBX_ * 32;                                                    \
  int bid = blockIdx.x;                                                         \
  int swzb = (bid & 7) * (nwg >> 3) + (bid >> 3); /* bijective: nwg%8==0 */     \
  const int n0 = (swzb % NBX_) * 256;                                           \
  const int m0 = (swzb / NBX_) * 256;                                           \
  f32x4 acc[8][4];                                                              \
  _Pragma("unroll") for (int i = 0; i < 8; ++i)                                 \
      _Pragma("unroll") for (int j = 0; j < 4; ++j)                             \
          _Pragma("unroll") for (int r = 0; r < 4; ++r) acc[i][j][r] = 0.0f;    \
  /* staging: thread owns 16B; chunk c covers rows c*64..c*64+63 of the tile. */\
  const int s_r = tid >> 3;                                                     \
  const int s_c = ((tid & 7) * 16) ^ ((s_r & 7) << 4); /* pre-swizzled col */   \
  const char* Agp = (const char*)A_ + (size_t)(m0 + s_r) * 2048 + s_c;          \
  const char* Bgp = (const char*)Bt_ + (size_t)(n0 + s_r) * 2048 + s_c;         \
  /* fragment-read geometry (swizzled) */                                       \
  const int colk0 = (g * 16) ^ ((fr & 7) << 4);                                 \
  const int colk1 = (64 + g * 16) ^ ((fr & 7) << 4);                            \
  const int arow = (wr * 128 + fr) * 128;                                       \
  const int brow = (wc * 64 + fr) * 128;                                        \
  bf16x8 avreg[4], bvreg[4];                                                    \
  /* prologue: tile 0 -> buf0, tile 1 -> buf1 (issue order matters for vmcnt) */\
  _Pragma("unroll") for (int c = 0; c < 4; ++c) { G8_STAGE(0, c, 0) }           \
  _Pragma("unroll") for (int c = 0; c < 4; ++c) { G8_STAGE(1, c, 128) }         \
  for (int it2 = 0; it2 < 8; ++it2) {                                          \
    const size_t koO = (size_t)(2 * it2 + 1) * 128;                             \
    const size_t koE = (size_t)(2 * it2 + 2 > 15 ? 15 : 2 * it2 + 2) * 128;     \
    /* phase 0: buf0, k-half 0, m-half 0 */                                     \
    if (it2) { G8_STAGE(1, 0, koO) VMC(2) } else { VMC(8) }                     \
    DSB; BARRIER; DSB;                                                          \
    G8_LDA(0, 0, colk0) G8_LDB(0, colk0)                                        \
    LGKM0 G8_MFMA(0) DSB; BARRIER; DSB;                                         \
    /* phase 1: buf0, k0, mh1 (bvreg reused) */                                 \
    G8_LDA(0, 1, colk0)                                                         \
    if (it2) { G8_STAGE(1, 1, koO) }                                            \
    DSB; BARRIER; DSB; LGKM0 G8_MFMA(1) DSB; BARRIER; DSB;                      \
    /* phase 2: buf0, k1, mh0 */                                                \
    G8_LDA(0, 0, colk1) G8_LDB(0, colk1)                                        \
    if (it2) { G8_STAGE(1, 2, koO) }                                            \
    DSB; BARRIER; DSB; LGKM0 G8_MFMA(0) DSB; BARRIER; DSB;                      \
    /* phase 3: buf0, k1, mh1 */                                                \
    G8_LDA(0, 1, colk1)                                                         \
    if (it2) { G8_STAGE(1, 3, koO) }                                            \
    DSB; BARRIER; DSB; LGKM0 G8_MFMA(1) DSB; BARRIER; DSB;                      \
    /* phase 4: buf1, k0, mh0 */                                                \
    G8_STAGE(0, 0, koE) VMC(2)                                                  \
    DSB; BARRIER; DSB;                                                          \
    G8_LDA(1, 0, colk0) G8_LDB(1, colk0)                                        \
    LGKM0 G8_MFMA(0) DSB; BARRIER; DSB;                                         \
    /* phase 5: buf1, k0, mh1 */                                                \
    G8_LDA(1, 1, colk0)                                                         \
    G8_STAGE(0, 1, koE)                                                         \
    DSB; BARRIER; DSB; LGKM0 G8_MFMA(1) DSB; BARRIER; DSB;                      \
    /* phase 6: buf1, k1, mh0 */                                                \
    G8_LDA(1, 0, colk1) G8_LDB(1, colk1)                                        \
    G8_STAGE(0, 2, koE)                                                         \
    DSB; BARRIER; DSB; LGKM0 G8_MFMA(0) DSB; BARRIER; DSB;                      \
    /* phase 7: buf1, k1, mh1 */                                                \
    G8_LDA(1, 1, colk1)                                                         \
    G8_STAGE(0, 3, koE)                                                         \
    DSB; BARRIER; DSB; LGKM0 G8_MFMA(1) DSB; BARRIER; DSB;                      \
  }

// QKV GEMM: N=3072. Epilogue scatters to Q (scaled 1/8) [BH][T][64], K [BH][T][64], VT [BH][64][T].
__global__ __launch_bounds__(512, 2) void gemm_qkv(
    const unsigned short* __restrict__ A, const unsigned short* __restrict__ Bt,
    const float* __restrict__ bias,
    unsigned short* __restrict__ Qo, unsigned short* __restrict__ Ko,
    unsigned short* __restrict__ VTo) {
  GEMM8_CORE(A, Bt, 12)
#pragma unroll
  for (int i = 0; i < 8; ++i) {
    int mb = m0 + wr * 128 + i * 16 + 4 * g;
    int bidx = mb >> 10;
    int t = mb & 1023;
#pragma unroll
    for (int j = 0; j < 4; ++j) {
      int n = n0 + wc * 64 + j * 16 + fr;
      float bv2 = bias[n];
      int part = n >> 10;
      int nn2 = n & 1023;
      int h = nn2 >> 6, d = nn2 & 63;
      if (part == 2) {
        alignas(8) unsigned short pk[4];
#pragma unroll
        for (int r = 0; r < 4; ++r) pk[r] = f2bf(acc[i][j][r] + bv2);
        *(ushort4*)&VTo[((size_t)(bidx * NHEAD + h) * HDIM + d) * SEQ + t] =
            *(const ushort4*)pk;
      } else {
        unsigned short* dst = (part == 0) ? Qo : Ko;
        float scl = (part == 0) ? 0.125f : 1.0f;   // fold 1/sqrt(hd) into Q
        size_t base = ((size_t)(bidx * NHEAD + h) * SEQ + t) * HDIM + d;
#pragma unroll
        for (int r = 0; r < 4; ++r)
          dst[base + (size_t)r * HDIM] = f2bf((acc[i][j][r] + bv2) * scl);
      }
    }
  }
}

// Proj GEMM: N=1024, f32 output + bias.
__global__ __launch_bounds__(512, 2) void gemm_proj(
    const unsigned short* __restrict__ A, const unsigned short* __restrict__ Bt,
    const float* __restrict__ bias, float* __restrict__ Out) {
  GEMM8_CORE(A, Bt, 4)
#pragma unroll
  for (int i = 0; i < 8; ++i) {
    int mb = m0 + wr * 128 + i * 16 + 4 * g;
#pragma unroll
    for (int j = 0; j < 4; ++j) {
      int n = n0 + wc * 64 + j * 16 + fr;
      float bv2 = bias[n];
#pragma unroll
      for (int r = 0; r < 4; ++r)
        Out[(size_t)(mb + r) * N_EMBD + n] = acc[i][j][r] + bv2;
    }
  }
}

// ---------------- flash-style causal attention (unchanged from R5) ----------------
__global__ __launch_bounds__(256) void attn_kernel(
    const unsigned short* __restrict__ Q, const unsigned short* __restrict__ Kv,
    const unsigned short* __restrict__ VT, unsigned short* __restrict__ Y) {
  __shared__ unsigned short Kt[2][4096];
  __shared__ unsigned short Vt[2][4096];
  __shared__ unsigned short p_lds[4 * 32 * 72];
  __shared__ float smx[4][32];
  int tid = threadIdx.x, l = tid & 63, w = tid >> 6;
  int orig = blockIdx.x;
  int swz = (orig & 7) * 128 + (orig >> 3);
  int bh = swz >> 3;
  int qi = 7 - (swz & 7);
  int b = bh >> 4, h = bh & 15;
  int q0 = qi * 128;
  int wq = q0 + w * 32;
  const unsigned short* Qb = Q + (size_t)bh * SEQ * HDIM;
  const char* Kc = (const char*)(Kv + (size_t)bh * SEQ * HDIM);
  const char* Vc = (const char*)(VT + (size_t)bh * HDIM * SEQ);
  unsigned short* pw = &p_lds[w * 32 * 72];
  const int g = l >> 4;
  const int fr = l & 15;

  const int P0 = tid * 16, P1 = tid * 16 + 4096;
  const int r0 = P0 >> 7, r1 = P1 >> 7;
  const int s0 = (P0 & 127) ^ ((r0 & 7) << 4);
  const int s1 = (P1 & 127) ^ ((r1 & 7) << 4);
  const char* Kg0 = Kc + r0 * 128 + s0;
  const char* Kg1 = Kc + r1 * 128 + s1;
  const char* Vg0 = Vc + (size_t)r0 * 2048 + s0;
  const char* Vg1 = Vc + (size_t)r1 * 2048 + s1;

  const int bc = (16 * g) ^ ((l & 7) << 4);

  bf16x8 aq[2][2];
#pragma unroll
  for (int i = 0; i < 2; ++i)
#pragma unroll
    for (int ik = 0; ik < 2; ++ik)
      aq[i][ik] = *(const bf16x8*)&Qb[(size_t)(wq + i * 16 + fr) * HDIM + ik * 32 + 8 * g];

  float mrun[2], lpart[2];
  mrun[0] = mrun[1] = -3.0e38f;
  lpart[0] = lpart[1] = 0.0f;
  f32x4 acc_o[2][4];
#pragma unroll
  for (int i = 0; i < 2; ++i)
#pragma unroll
    for (int jd = 0; jd < 4; ++jd)
#pragma unroll
      for (int r = 0; r < 4; ++r) acc_o[i][jd][r] = 0.0f;

  const int n_it = (q0 + 128) >> 6;

  gload_lds16((const unsigned short*)(Kg0), &Kt[0][P0 >> 1]);
  gload_lds16((const unsigned short*)(Kg1), &Kt[0][P1 >> 1]);
  gload_lds16((const unsigned short*)(Vg0), &Vt[0][P0 >> 1]);
  gload_lds16((const unsigned short*)(Vg1), &Vt[0][P1 >> 1]);

  for (int it = 0; it < n_it; ++it) {
    const int kv0 = it << 6;
    const int cur = it & 1;
    if (it + 1 < n_it) {
      const int nx = kv0 + 64;
      gload_lds16((const unsigned short*)(Kg0 + nx * 128), &Kt[cur ^ 1][P0 >> 1]);
      gload_lds16((const unsigned short*)(Kg1 + nx * 128), &Kt[cur ^ 1][P1 >> 1]);
      gload_lds16((const unsigned short*)(Vg0 + nx * 2),   &Vt[cur ^ 1][P0 >> 1]);
      gload_lds16((const unsigned short*)(Vg1 + nx * 2),   &Vt[cur ^ 1][P1 >> 1]);
      asm volatile("s_waitcnt vmcnt(4)" ::: "memory");
    } else {
      asm volatile("s_waitcnt vmcnt(0)" ::: "memory");
    }
    __builtin_amdgcn_sched_barrier(0);
    __builtin_amdgcn_s_barrier();
    __builtin_amdgcn_sched_barrier(0);

    const char* Kbuf = (const char*)Kt[cur];
    const char* Vbuf = (const char*)Vt[cur];

    f32x4 s2[2][4];
#pragma unroll
    for (int i = 0; i < 2; ++i)
#pragma unroll
      for (int j = 0; j < 4; ++j)
#pragma unroll
        for (int r = 0; r < 4; ++r) s2[i][j][r] = 0.0f;

    __builtin_amdgcn_s_setprio(1);
#pragma unroll
    for (int ik = 0; ik < 2; ++ik) {
#pragma unroll
      for (int j = 0; j < 4; ++j) {
        bf16x8 bk = *(const bf16x8*)(Kbuf + (j * 16 + fr) * 128 + (bc ^ (ik << 6)));
#pragma unroll
        for (int i = 0; i < 2; ++i) s2[i][j] = mfma_bf16(bk, aq[i][ik], s2[i][j]);
      }
    }
    __builtin_amdgcn_s_setprio(0);

    bool need_mask = (kv0 + 63) > wq;
    if (need_mask) {
#pragma unroll
      for (int i = 0; i < 2; ++i) {
        int q = wq + i * 16 + fr;
#pragma unroll
        for (int j = 0; j < 4; ++j)
#pragma unroll
          for (int r = 0; r < 4; ++r) {
            int kv = kv0 + j * 16 + 4 * g + r;
            if (kv > q) s2[i][j][r] = -3.0e38f;
          }
      }
    }

    float pm[2];
#pragma unroll
    for (int i = 0; i < 2; ++i) {
      float m01 = fmaxf(fmaxf(s2[i][0][0], s2[i][0][1]), fmaxf(s2[i][0][2], s2[i][0][3]));
      float m11 = fmaxf(fmaxf(s2[i][1][0], s2[i][1][1]), fmaxf(s2[i][1][2], s2[i][1][3]));
      float m21 = fmaxf(fmaxf(s2[i][2][0], s2[i][2][1]), fmaxf(s2[i][2][2], s2[i][2][3]));
      float m31 = fmaxf(fmaxf(s2[i][3][0], s2[i][3][1]), fmaxf(s2[i][3][2], s2[i][3][3]));
      float mm = fmaxf(fmaxf(m01, m11), fmaxf(m21, m31));
      mm = fmaxf(mm, __shfl_xor(mm, 16, 64));
      mm = fmaxf(mm, __shfl_xor(mm, 32, 64));
      pm[i] = mm;
    }

    bool okl = (pm[0] <= mrun[0] + 8.0f) && (pm[1] <= mrun[1] + 8.0f);
    if (!__all(okl)) {
#pragma unroll
      for (int i = 0; i < 2; ++i) {
        float mn = fmaxf(mrun[i], pm[i]);
        float sc = __expf(mrun[i] - mn);
        mrun[i] = mn;
        lpart[i] *= sc;
        if (g == 0) smx[w][i * 16 + fr] = sc;
      }
      asm volatile("s_waitcnt lgkmcnt(0)" ::: "memory");
#pragma unroll
      for (int i = 0; i < 2; ++i)
#pragma unroll
        for (int r = 0; r < 4; ++r) {
          float sc = smx[w][i * 16 + 4 * g + r];
#pragma unroll
          for (int jd = 0; jd < 4; ++jd) acc_o[i][jd][r] *= sc;
        }
    }

#pragma unroll
    for (int i = 0; i < 2; ++i) {
#pragma unroll
      for (int j = 0; j < 4; ++j) {
        float p0 = __expf(s2[i][j][0] - mrun[i]);
        float p1 = __expf(s2[i][j][1] - mrun[i]);
        float p2 = __expf(s2[i][j][2] - mrun[i]);
        float p3 = __expf(s2[i][j][3] - mrun[i]);
        lpart[i] += (p0 + p1) + (p2 + p3);
        ushort4 pk;
        pk.x = f2bf(p0); pk.y = f2bf(p1); pk.z = f2bf(p2); pk.w = f2bf(p3);
        *(ushort4*)&pw[(i * 16 + fr) * 72 + j * 16 + 4 * g] = pk;
      }
    }

    __builtin_amdgcn_s_setprio(1);
#pragma unroll
    for (int ik2 = 0; ik2 < 2; ++ik2) {
      bf16x8 ap[2];
#pragma unroll
      for (int i = 0; i < 2; ++i)
        ap[i] = *(const bf16x8*)&pw[(i * 16 + fr) * 72 + ik2 * 32 + 8 * g];
#pragma unroll
      for (int jd = 0; jd < 4; ++jd) {
        bf16x8 bv = *(const bf16x8*)(Vbuf + (jd * 16 + fr) * 128 + (bc ^ (ik2 << 6)));
#pragma unroll
        for (int i = 0; i < 2; ++i) acc_o[i][jd] = mfma_bf16(ap[i], bv, acc_o[i][jd]);
      }
    }
    __builtin_amdgcn_s_setprio(0);

    asm volatile("s_waitcnt lgkmcnt(0)" ::: "memory");
    __builtin_amdgcn_sched_barrier(0);
    __builtin_amdgcn_s_barrier();
    __builtin_amdgcn_sched_barrier(0);
  }

#pragma unroll
  for (int i = 0; i < 2; ++i) {
    float t = lpart[i];
    t += __shfl_xor(t, 16, 64);
    t += __shfl_xor(t, 32, 64);
    if (g == 0) smx[w][i * 16 + fr] = t;
  }
  asm volatile("s_waitcnt lgkmcnt(0)" ::: "memory");
#pragma unroll
  for (int i = 0; i < 2; ++i)
#pragma unroll
    for (int r = 0; r < 4; ++r) {
      float inv = 1.0f / smx[w][i * 16 + 4 * g + r];
      int q = wq + i * 16 + 4 * g + r;
#pragma unroll
      for (int jd = 0; jd < 4; ++jd)
        Y[((size_t)b * SEQ + q) * N_EMBD + h * HDIM + jd * 16 + fr] =
            f2bf(acc_o[i][jd][r] * inv);
    }
}

// ---------------- launcher ----------------
extern "C" void kernel_launch(void* const* d_in, const int* in_sizes, int n_in,
                              void* d_out, int out_size, void* d_ws, size_t ws_size,
                              hipStream_t stream) {
  (void)in_sizes; (void)n_in; (void)out_size; (void)ws_size;
  const float* x      = (const float*)d_in[0];
  const float* w_attn = (const float*)d_in[1];
  const float* b_attn = (const float*)d_in[2];
  const float* w_proj = (const float*)d_in[3];
  const float* b_proj = (const float*)d_in[4];
  float* out = (float*)d_out;

  char* ws = (char*)d_ws;
  size_t off = 0;
  auto carve = [&](size_t bytes) -> char* {
    char* p = ws + off;
    off += (bytes + 255) & ~(size_t)255;
    return p;
  };
  unsigned short* xb     = (unsigned short*)carve((size_t)MROWS * N_EMBD * 2);
  unsigned short* wTattn = (unsigned short*)carve((size_t)3 * N_EMBD * N_EMBD * 2);
  unsigned short* wTproj = (unsigned short*)carve((size_t)N_EMBD * N_EMBD * 2);
  unsigned short* Qb     = (unsigned short*)carve((size_t)MROWS * N_EMBD * 2);
  unsigned short* Kb     = (unsigned short*)carve((size_t)MROWS * N_EMBD * 2);
  unsigned short* VTb    = (unsigned short*)carve((size_t)MROWS * N_EMBD * 2);
  unsigned short* Yb     = (unsigned short*)carve((size_t)MROWS * N_EMBD * 2);
  carve(4096);  // slack so proj's clamped tail prefetch stays in-bounds

  cast_f32_bf16<<<dim3(MROWS * N_EMBD / 1024), 256, 0, stream>>>(x, xb, MROWS * N_EMBD);
  transpose_cast<<<dim3(3 * N_EMBD / 64, N_EMBD / 64), 256, 0, stream>>>(w_attn, wTattn, N_EMBD, 3 * N_EMBD);
  transpose_cast<<<dim3(N_EMBD / 64, N_EMBD / 64), 256, 0, stream>>>(w_proj, wTproj, N_EMBD, N_EMBD);
  gemm_qkv<<<dim3(12 * 32), 512, 0, stream>>>(xb, wTattn, b_attn, Qb, Kb, VTb);
  attn_kernel<<<dim3(BATCH * NHEAD * (SEQ / 128)), 256, 0, stream>>>(Qb, Kb, VTb, Yb);
  gemm_proj<<<dim3(4 * 32), 512, 0, stream>>>(Yb, wTproj, b_proj, out);
}

// Round 7
// 193.453 us; speedup vs baseline: 1.0240x; 1.0240x over previous
//
#include <hip/hip_runtime.h>
#include <stdint.h>

#define N_EMBD 1024
#define NHEAD  16
#define HDIM   64
#define BATCH  8
#define SEQ    1024
#define MROWS  (BATCH*SEQ)   // 8192

typedef __bf16 bf16x8 __attribute__((ext_vector_type(8)));
typedef float  f32x4  __attribute__((ext_vector_type(4)));

__device__ inline unsigned short f2bf(float f) {
  uint32_t u = __float_as_uint(f);
  u += 0x7FFFu + ((u >> 16) & 1u);   // RNE; inputs are finite
  return (unsigned short)(u >> 16);
}

__device__ inline f32x4 mfma_bf16(bf16x8 a, bf16x8 b, f32x4 c) {
  return __builtin_amdgcn_mfma_f32_16x16x32_bf16(a, b, c, 0, 0, 0);
}

__device__ inline void gload_lds16(const unsigned short* g, unsigned short* l) {
  __builtin_amdgcn_global_load_lds(
      (const __attribute__((address_space(1))) void*)g,
      (__attribute__((address_space(3))) void*)l,
      16, 0, 0);
}

#define DSB __builtin_amdgcn_sched_barrier(0)
#define BARRIER __builtin_amdgcn_s_barrier()
#define VMC_(n) asm volatile("s_waitcnt vmcnt(" #n ")" ::: "memory")
#define VMC(n) VMC_(n)
#define LGKM0 asm volatile("s_waitcnt lgkmcnt(0)" ::: "memory"); DSB

// ---------------- cast f32 -> bf16 (vectorized) ----------------
__global__ __launch_bounds__(256) void cast_f32_bf16(
    const float* __restrict__ in, unsigned short* __restrict__ out, int n) {
  int i = (blockIdx.x * 256 + threadIdx.x) * 4;
  if (i >= n) return;
  float4 v = *(const float4*)(in + i);
  ushort4 o;
  o.x = f2bf(v.x); o.y = f2bf(v.y); o.z = f2bf(v.z); o.w = f2bf(v.w);
  *(ushort4*)(out + i) = o;
}

// ---------------- transpose + cast: in [K][N] f32 -> out [N][K] bf16 ----------------
__global__ __launch_bounds__(256) void transpose_cast(
    const float* __restrict__ in, unsigned short* __restrict__ out, int K, int N) {
  __shared__ unsigned short tile[64 * 72];
  int k0 = blockIdx.y * 64, n0 = blockIdx.x * 64;
  int t = threadIdx.x;
  {
    int col = (t & 15) * 4;
#pragma unroll
    for (int it = 0; it < 4; ++it) {
      int row = (t >> 4) + it * 16;
      float4 v = *(const float4*)(in + (size_t)(k0 + row) * N + n0 + col);
      ushort4 o;
      o.x = f2bf(v.x); o.y = f2bf(v.y); o.z = f2bf(v.z); o.w = f2bf(v.w);
      *(ushort4*)&tile[row * 72 + col] = o;
    }
  }
  __syncthreads();
  {
    int kcol = (t & 7) * 8;
#pragma unroll
    for (int it = 0; it < 2; ++it) {
      int nrow = (t >> 3) + it * 32;
      alignas(16) unsigned short tmp[8];
#pragma unroll
      for (int j = 0; j < 8; ++j) tmp[j] = tile[(kcol + j) * 72 + nrow];
      *(uint4*)(out + (size_t)(n0 + nrow) * K + k0 + kcol) = *(const uint4*)tmp;
    }
  }
}

// ---------------- GEMM v4: ring-4 pipeline, BK=32, transposed-granule LDS ----------------
// 8 waves (2M x 4N). LDS granule = 16 rows x 64B(K=32), stored transposed:
//   lds[gran*1024 + fr*64 + g*16] = G[row16*gran + fr][k-bytes g*16..g*16+15]
// Staging: linear LDS dest (base+lane*16), pre-gathered global source (rule #21).
// Step t: stage tile t+3 -> slot (t+3)&3; vmcnt(3*calls) waits only 3-step-old loads;
// barrier; ds_read slot t&3; lgkm0; barrier (frees slot for t+1's stage); MFMA.

#define RING_STEP(S, VN)                                                         \
  {                                                                              \
    const int stg = (kt + 3 > 31) ? 31 : kt + 3;                                 \
    _Pragma("unroll") for (int c = 0; c < kACALLS; ++c)                          \
      gload_lds16((const unsigned short*)(srcA[c] + stg * 64),                   \
                  &Asl[(S + 3) & 3][ldsA[c]]);                                   \
    _Pragma("unroll") for (int c = 0; c < kBCALLS; ++c)                          \
      gload_lds16((const unsigned short*)(srcB[c] + stg * 64),                   \
                  &Bsl[(S + 3) & 3][ldsB[c]]);                                   \
    VMC(VN); DSB; BARRIER; DSB;                                                  \
    bf16x8 av[kMFR], bv[kNFR];                                                   \
    _Pragma("unroll") for (int m = 0; m < kMFR; ++m)                             \
      av[m] = *(const bf16x8*)((const char*)&Asl[S][0] + (wrg + m) * 1024 + rb); \
    _Pragma("unroll") for (int n = 0; n < kNFR; ++n)                             \
      bv[n] = *(const bf16x8*)((const char*)&Bsl[S][0] + (wcg + n) * 1024 + rb); \
    LGKM0; BARRIER; DSB;                                                         \
    __builtin_amdgcn_s_setprio(1);                                               \
    _Pragma("unroll") for (int n = 0; n < kNFR; ++n)                             \
      _Pragma("unroll") for (int m = 0; m < kMFR; ++m)                           \
        acc[m][n] = mfma_bf16(av[m], bv[n], acc[m][n]);                          \
    __builtin_amdgcn_s_setprio(0);                                               \
    ++kt;                                                                        \
  }

#define RING_CORE(A_, Bt_, NBX_, AG, BG, MFR, NFR, ACALLS, BCALLS, VMCN)         \
  __shared__ unsigned short Asl[4][(AG) * 512];                                  \
  __shared__ unsigned short Bsl[4][(BG) * 512];                                  \
  enum { kMFR = (MFR), kNFR = (NFR), kACALLS = (ACALLS), kBCALLS = (BCALLS) };   \
  const int tid = threadIdx.x;                                                   \
  const int l = tid & 63, w = tid >> 6;                                          \
  const int wr = w >> 2, wc = w & 3;                                             \
  const int g = l >> 4, fr = l & 15;                                             \
  const int nwg = (MROWS / ((AG) * 16)) * (NBX_);                                \
  int bid = blockIdx.x;                                                          \
  int swzb = (bid & 7) * (nwg >> 3) + (bid >> 3); /* bijective: nwg%8==0 */      \
  const int n0 = (swzb % (NBX_)) * ((BG) * 16);                                  \
  const int m0 = (swzb / (NBX_)) * ((AG) * 16);                                  \
  f32x4 acc[kMFR][kNFR];                                                         \
  _Pragma("unroll") for (int i = 0; i < kMFR; ++i)                               \
    _Pragma("unroll") for (int j = 0; j < kNFR; ++j)                             \
      _Pragma("unroll") for (int r = 0; r < 4; ++r) acc[i][j][r] = 0.0f;         \
  const char* srcA[kACALLS]; int ldsA[kACALLS];                                  \
  const char* srcB[kBCALLS]; int ldsB[kBCALLS];                                  \
  _Pragma("unroll") for (int c = 0; c < kACALLS; ++c) {                          \
    int o = (c * 8192 + tid * 16) % ((AG) * 1024);                               \
    ldsA[c] = o >> 1;                                                            \
    srcA[c] = (const char*)(A_) +                                                \
              (size_t)(m0 + (o >> 10) * 16 + ((o >> 6) & 15)) * 2048 +           \
              ((o >> 4) & 3) * 16;                                               \
  }                                                                              \
  _Pragma("unroll") for (int c = 0; c < kBCALLS; ++c) {                          \
    int o = (c * 8192 + tid * 16) % ((BG) * 1024);                               \
    ldsB[c] = o >> 1;                                                            \
    srcB[c] = (const char*)(Bt_) +                                               \
              (size_t)(n0 + (o >> 10) * 16 + ((o >> 6) & 15)) * 2048 +           \
              ((o >> 4) & 3) * 16;                                               \
  }                                                                              \
  const int wrg = wr * ((AG) / 2);                                               \
  const int wcg = wc * ((BG) / 4);                                               \
  const int rb = fr * 64 + g * 16;                                               \
  _Pragma("unroll") for (int s = 0; s < 3; ++s) {                                \
    _Pragma("unroll") for (int c = 0; c < kACALLS; ++c)                          \
      gload_lds16((const unsigned short*)(srcA[c] + s * 64), &Asl[s][ldsA[c]]);  \
    _Pragma("unroll") for (int c = 0; c < kBCALLS; ++c)                          \
      gload_lds16((const unsigned short*)(srcB[c] + s * 64), &Bsl[s][ldsB[c]]);  \
  }                                                                              \
  int kt = 0;                                                                    \
  for (int it8 = 0; it8 < 8; ++it8) {                                            \
    RING_STEP(0, VMCN) RING_STEP(1, VMCN) RING_STEP(2, VMCN) RING_STEP(3, VMCN)  \
  }

// QKV GEMM: 256x192 tile, grid 32x16=512 (2 exact rounds). Scatters Q(1/8)/K/VT.
__global__ __launch_bounds__(512) void gemm_qkv(
    const unsigned short* __restrict__ A, const unsigned short* __restrict__ Bt,
    const float* __restrict__ bias,
    unsigned short* __restrict__ Qo, unsigned short* __restrict__ Ko,
    unsigned short* __restrict__ VTo) {
  RING_CORE(A, Bt, 16, 16, 12, 8, 3, 2, 2, 12)
#pragma unroll
  for (int i = 0; i < kMFR; ++i) {
    int mb = m0 + wrg * 16 + i * 16 + 4 * g;
    int bidx = mb >> 10;
    int t = mb & 1023;
#pragma unroll
    for (int j = 0; j < kNFR; ++j) {
      int n = n0 + wcg * 16 + j * 16 + fr;
      float bv2 = bias[n];
      int part = n >> 10;
      int nn2 = n & 1023;
      int h = nn2 >> 6, d = nn2 & 63;
      if (part == 2) {
        alignas(8) unsigned short pk[4];
#pragma unroll
        for (int r = 0; r < 4; ++r) pk[r] = f2bf(acc[i][j][r] + bv2);
        *(ushort4*)&VTo[((size_t)(bidx * NHEAD + h) * HDIM + d) * SEQ + t] =
            *(const ushort4*)pk;
      } else {
        unsigned short* dst = (part == 0) ? Qo : Ko;
        float scl = (part == 0) ? 0.125f : 1.0f;   // fold 1/sqrt(hd) into Q
        size_t base = ((size_t)(bidx * NHEAD + h) * SEQ + t) * HDIM + d;
#pragma unroll
        for (int r = 0; r < 4; ++r)
          dst[base + (size_t)r * HDIM] = f2bf((acc[i][j][r] + bv2) * scl);
      }
    }
  }
}

// Proj GEMM: 128x256 tile, grid 64x4=256 (1 exact round). f32 out + bias.
__global__ __launch_bounds__(512) void gemm_proj(
    const unsigned short* __restrict__ A, const unsigned short* __restrict__ Bt,
    const float* __restrict__ bias, float* __restrict__ Out) {
  RING_CORE(A, Bt, 4, 8, 16, 4, 4, 1, 2, 9)
#pragma unroll
  for (int i = 0; i < kMFR; ++i) {
    int mb = m0 + wrg * 16 + i * 16 + 4 * g;
#pragma unroll
    for (int j = 0; j < kNFR; ++j) {
      int n = n0 + wcg * 16 + j * 16 + fr;
      float bv2 = bias[n];
#pragma unroll
      for (int r = 0; r < 4; ++r)
        Out[(size_t)(mb + r) * N_EMBD + n] = acc[i][j][r] + bv2;
    }
  }
}

// ---------------- flash-style causal attention (unchanged from R5) ----------------
__global__ __launch_bounds__(256) void attn_kernel(
    const unsigned short* __restrict__ Q, const unsigned short* __restrict__ Kv,
    const unsigned short* __restrict__ VT, unsigned short* __restrict__ Y) {
  __shared__ unsigned short Kt[2][4096];
  __shared__ unsigned short Vt[2][4096];
  __shared__ unsigned short p_lds[4 * 32 * 72];
  __shared__ float smx[4][32];
  int tid = threadIdx.x, l = tid & 63, w = tid >> 6;
  int orig = blockIdx.x;
  int swz = (orig & 7) * 128 + (orig >> 3);
  int bh = swz >> 3;
  int qi = 7 - (swz & 7);
  int b = bh >> 4, h = bh & 15;
  int q0 = qi * 128;
  int wq = q0 + w * 32;
  const unsigned short* Qb = Q + (size_t)bh * SEQ * HDIM;
  const char* Kc = (const char*)(Kv + (size_t)bh * SEQ * HDIM);
  const char* Vc = (const char*)(VT + (size_t)bh * HDIM * SEQ);
  unsigned short* pw = &p_lds[w * 32 * 72];
  const int g = l >> 4;
  const int fr = l & 15;

  const int P0 = tid * 16, P1 = tid * 16 + 4096;
  const int r0 = P0 >> 7, r1 = P1 >> 7;
  const int s0 = (P0 & 127) ^ ((r0 & 7) << 4);
  const int s1 = (P1 & 127) ^ ((r1 & 7) << 4);
  const char* Kg0 = Kc + r0 * 128 + s0;
  const char* Kg1 = Kc + r1 * 128 + s1;
  const char* Vg0 = Vc + (size_t)r0 * 2048 + s0;
  const char* Vg1 = Vc + (size_t)r1 * 2048 + s1;

  const int bc = (16 * g) ^ ((l & 7) << 4);

  bf16x8 aq[2][2];
#pragma unroll
  for (int i = 0; i < 2; ++i)
#pragma unroll
    for (int ik = 0; ik < 2; ++ik)
      aq[i][ik] = *(const bf16x8*)&Qb[(size_t)(wq + i * 16 + fr) * HDIM + ik * 32 + 8 * g];

  float mrun[2], lpart[2];
  mrun[0] = mrun[1] = -3.0e38f;
  lpart[0] = lpart[1] = 0.0f;
  f32x4 acc_o[2][4];
#pragma unroll
  for (int i = 0; i < 2; ++i)
#pragma unroll
    for (int jd = 0; jd < 4; ++jd)
#pragma unroll
      for (int r = 0; r < 4; ++r) acc_o[i][jd][r] = 0.0f;

  const int n_it = (q0 + 128) >> 6;

  gload_lds16((const unsigned short*)(Kg0), &Kt[0][P0 >> 1]);
  gload_lds16((const unsigned short*)(Kg1), &Kt[0][P1 >> 1]);
  gload_lds16((const unsigned short*)(Vg0), &Vt[0][P0 >> 1]);
  gload_lds16((const unsigned short*)(Vg1), &Vt[0][P1 >> 1]);

  for (int it = 0; it < n_it; ++it) {
    const int kv0 = it << 6;
    const int cur = it & 1;
    if (it + 1 < n_it) {
      const int nx = kv0 + 64;
      gload_lds16((const unsigned short*)(Kg0 + nx * 128), &Kt[cur ^ 1][P0 >> 1]);
      gload_lds16((const unsigned short*)(Kg1 + nx * 128), &Kt[cur ^ 1][P1 >> 1]);
      gload_lds16((const unsigned short*)(Vg0 + nx * 2),   &Vt[cur ^ 1][P0 >> 1]);
      gload_lds16((const unsigned short*)(Vg1 + nx * 2),   &Vt[cur ^ 1][P1 >> 1]);
      asm volatile("s_waitcnt vmcnt(4)" ::: "memory");
    } else {
      asm volatile("s_waitcnt vmcnt(0)" ::: "memory");
    }
    __builtin_amdgcn_sched_barrier(0);
    __builtin_amdgcn_s_barrier();
    __builtin_amdgcn_sched_barrier(0);

    const char* Kbuf = (const char*)Kt[cur];
    const char* Vbuf = (const char*)Vt[cur];

    f32x4 s2[2][4];
#pragma unroll
    for (int i = 0; i < 2; ++i)
#pragma unroll
      for (int j = 0; j < 4; ++j)
#pragma unroll
        for (int r = 0; r < 4; ++r) s2[i][j][r] = 0.0f;

    __builtin_amdgcn_s_setprio(1);
#pragma unroll
    for (int ik = 0; ik < 2; ++ik) {
#pragma unroll
      for (int j = 0; j < 4; ++j) {
        bf16x8 bk = *(const bf16x8*)(Kbuf + (j * 16 + fr) * 128 + (bc ^ (ik << 6)));
#pragma unroll
        for (int i = 0; i < 2; ++i) s2[i][j] = mfma_bf16(bk, aq[i][ik], s2[i][j]);
      }
    }
    __builtin_amdgcn_s_setprio(0);

    bool need_mask = (kv0 + 63) > wq;
    if (need_mask) {
#pragma unroll
      for (int i = 0; i < 2; ++i) {
        int q = wq + i * 16 + fr;
#pragma unroll
        for (int j = 0; j < 4; ++j)
#pragma unroll
          for (int r = 0; r < 4; ++r) {
            int kv = kv0 + j * 16 + 4 * g + r;
            if (kv > q) s2[i][j][r] = -3.0e38f;
          }
      }
    }

    float pm[2];
#pragma unroll
    for (int i = 0; i < 2; ++i) {
      float m01 = fmaxf(fmaxf(s2[i][0][0], s2[i][0][1]), fmaxf(s2[i][0][2], s2[i][0][3]));
      float m11 = fmaxf(fmaxf(s2[i][1][0], s2[i][1][1]), fmaxf(s2[i][1][2], s2[i][1][3]));
      float m21 = fmaxf(fmaxf(s2[i][2][0], s2[i][2][1]), fmaxf(s2[i][2][2], s2[i][2][3]));
      float m31 = fmaxf(fmaxf(s2[i][3][0], s2[i][3][1]), fmaxf(s2[i][3][2], s2[i][3][3]));
      float mm = fmaxf(fmaxf(m01, m11), fmaxf(m21, m31));
      mm = fmaxf(mm, __shfl_xor(mm, 16, 64));
      mm = fmaxf(mm, __shfl_xor(mm, 32, 64));
      pm[i] = mm;
    }

    bool okl = (pm[0] <= mrun[0] + 8.0f) && (pm[1] <= mrun[1] + 8.0f);
    if (!__all(okl)) {
#pragma unroll
      for (int i = 0; i < 2; ++i) {
        float mn = fmaxf(mrun[i], pm[i]);
        float sc = __expf(mrun[i] - mn);
        mrun[i] = mn;
        lpart[i] *= sc;
        if (g == 0) smx[w][i * 16 + fr] = sc;
      }
      asm volatile("s_waitcnt lgkmcnt(0)" ::: "memory");
#pragma unroll
      for (int i = 0; i < 2; ++i)
#pragma unroll
        for (int r = 0; r < 4; ++r) {
          float sc = smx[w][i * 16 + 4 * g + r];
#pragma unroll
          for (int jd = 0; jd < 4; ++jd) acc_o[i][jd][r] *= sc;
        }
    }

#pragma unroll
    for (int i = 0; i < 2; ++i) {
#pragma unroll
      for (int j = 0; j < 4; ++j) {
        float p0 = __expf(s2[i][j][0] - mrun[i]);
        float p1 = __expf(s2[i][j][1] - mrun[i]);
        float p2 = __expf(s2[i][j][2] - mrun[i]);
        float p3 = __expf(s2[i][j][3] - mrun[i]);
        lpart[i] += (p0 + p1) + (p2 + p3);
        ushort4 pk;
        pk.x = f2bf(p0); pk.y = f2bf(p1); pk.z = f2bf(p2); pk.w = f2bf(p3);
        *(ushort4*)&pw[(i * 16 + fr) * 72 + j * 16 + 4 * g] = pk;
      }
    }

    __builtin_amdgcn_s_setprio(1);
#pragma unroll
    for (int ik2 = 0; ik2 < 2; ++ik2) {
      bf16x8 ap[2];
#pragma unroll
      for (int i = 0; i < 2; ++i)
        ap[i] = *(const bf16x8*)&pw[(i * 16 + fr) * 72 + ik2 * 32 + 8 * g];
#pragma unroll
      for (int jd = 0; jd < 4; ++jd) {
        bf16x8 bv = *(const bf16x8*)(Vbuf + (jd * 16 + fr) * 128 + (bc ^ (ik2 << 6)));
#pragma unroll
        for (int i = 0; i < 2; ++i) acc_o[i][jd] = mfma_bf16(ap[i], bv, acc_o[i][jd]);
      }
    }
    __builtin_amdgcn_s_setprio(0);

    asm volatile("s_waitcnt lgkmcnt(0)" ::: "memory");
    __builtin_amdgcn_sched_barrier(0);
    __builtin_amdgcn_s_barrier();
    __builtin_amdgcn_sched_barrier(0);
  }

#pragma unroll
  for (int i = 0; i < 2; ++i) {
    float t = lpart[i];
    t += __shfl_xor(t, 16, 64);
    t += __shfl_xor(t, 32, 64);
    if (g == 0) smx[w][i * 16 + fr] = t;
  }
  asm volatile("s_waitcnt lgkmcnt(0)" ::: "memory");
#pragma unroll
  for (int i = 0; i < 2; ++i)
#pragma unroll
    for (int r = 0; r < 4; ++r) {
      float inv = 1.0f / smx[w][i * 16 + 4 * g + r];
      int q = wq + i * 16 + 4 * g + r;
#pragma unroll
      for (int jd = 0; jd < 4; ++jd)
        Y[((size_t)b * SEQ + q) * N_EMBD + h * HDIM + jd * 16 + fr] =
            f2bf(acc_o[i][jd][r] * inv);
    }
}

// ---------------- launcher ----------------
extern "C" void kernel_launch(void* const* d_in, const int* in_sizes, int n_in,
                              void* d_out, int out_size, void* d_ws, size_t ws_size,
                              hipStream_t stream) {
  (void)in_sizes; (void)n_in; (void)out_size; (void)ws_size;
  const float* x      = (const float*)d_in[0];
  const float* w_attn = (const float*)d_in[1];
  const float* b_attn = (const float*)d_in[2];
  const float* w_proj = (const float*)d_in[3];
  const float* b_proj = (const float*)d_in[4];
  float* out = (float*)d_out;

  char* ws = (char*)d_ws;
  size_t off = 0;
  auto carve = [&](size_t bytes) -> char* {
    char* p = ws + off;
    off += (bytes + 255) & ~(size_t)255;
    return p;
  };
  unsigned short* xb     = (unsigned short*)carve((size_t)MROWS * N_EMBD * 2);
  unsigned short* wTattn = (unsigned short*)carve((size_t)3 * N_EMBD * N_EMBD * 2);
  unsigned short* wTproj = (unsigned short*)carve((size_t)N_EMBD * N_EMBD * 2);
  unsigned short* Qb     = (unsigned short*)carve((size_t)MROWS * N_EMBD * 2);
  unsigned short* Kb     = (unsigned short*)carve((size_t)MROWS * N_EMBD * 2);
  unsigned short* VTb    = (unsigned short*)carve((size_t)MROWS * N_EMBD * 2);
  unsigned short* Yb     = (unsigned short*)carve((size_t)MROWS * N_EMBD * 2);
  carve(4096);

  cast_f32_bf16<<<dim3(MROWS * N_EMBD / 1024), 256, 0, stream>>>(x, xb, MROWS * N_EMBD);
  transpose_cast<<<dim3(3 * N_EMBD / 64, N_EMBD / 64), 256, 0, stream>>>(w_attn, wTattn, N_EMBD, 3 * N_EMBD);
  transpose_cast<<<dim3(N_EMBD / 64, N_EMBD / 64), 256, 0, stream>>>(w_proj, wTproj, N_EMBD, N_EMBD);
  gemm_qkv<<<dim3(512), 512, 0, stream>>>(xb, wTattn, b_attn, Qb, Kb, VTb);
  attn_kernel<<<dim3(BATCH * NHEAD * (SEQ / 128)), 256, 0, stream>>>(Qb, Kb, VTb, Yb);
  gemm_proj<<<dim3(256), 512, 0, stream>>>(Yb, wTproj, b_proj, out);
}

// Round 8
// 192.403 us; speedup vs baseline: 1.0296x; 1.0055x over previous
//
#include <hip/hip_runtime.h>
#include <stdint.h>

#define N_EMBD 1024
#define NHEAD  16
#define HDIM   64
#define BATCH  8
#define SEQ    1024
#define MROWS  (BATCH*SEQ)   // 8192

typedef __bf16 bf16x8 __attribute__((ext_vector_type(8)));
typedef float  f32x4  __attribute__((ext_vector_type(4)));

__device__ inline unsigned short f2bf(float f) {
  uint32_t u = __float_as_uint(f);
  u += 0x7FFFu + ((u >> 16) & 1u);   // RNE; inputs are finite
  return (unsigned short)(u >> 16);
}

__device__ inline f32x4 mfma_bf16(bf16x8 a, bf16x8 b, f32x4 c) {
  return __builtin_amdgcn_mfma_f32_16x16x32_bf16(a, b, c, 0, 0, 0);
}

__device__ inline void gload_lds16(const unsigned short* g, unsigned short* l) {
  __builtin_amdgcn_global_load_lds(
      (const __attribute__((address_space(1))) void*)g,
      (__attribute__((address_space(3))) void*)l,
      16, 0, 0);
}

#define DSB __builtin_amdgcn_sched_barrier(0)
#define BARRIER __builtin_amdgcn_s_barrier()
#define VMC_(n) asm volatile("s_waitcnt vmcnt(" #n ")" ::: "memory")
#define VMC(n) VMC_(n)
#define LGKM0 asm volatile("s_waitcnt lgkmcnt(0)" ::: "memory"); DSB

// ---------------- cast f32 -> bf16 (vectorized) ----------------
__global__ __launch_bounds__(256) void cast_f32_bf16(
    const float* __restrict__ in, unsigned short* __restrict__ out, int n) {
  int i = (blockIdx.x * 256 + threadIdx.x) * 4;
  if (i >= n) return;
  float4 v = *(const float4*)(in + i);
  ushort4 o;
  o.x = f2bf(v.x); o.y = f2bf(v.y); o.z = f2bf(v.z); o.w = f2bf(v.w);
  *(ushort4*)(out + i) = o;
}

// ---------------- transpose + cast: in [K][N] f32 -> out [N][K] bf16 ----------------
__global__ __launch_bounds__(256) void transpose_cast(
    const float* __restrict__ in, unsigned short* __restrict__ out, int K, int N) {
  __shared__ unsigned short tile[64 * 72];
  int k0 = blockIdx.y * 64, n0 = blockIdx.x * 64;
  int t = threadIdx.x;
  {
    int col = (t & 15) * 4;
#pragma unroll
    for (int it = 0; it < 4; ++it) {
      int row = (t >> 4) + it * 16;
      float4 v = *(const float4*)(in + (size_t)(k0 + row) * N + n0 + col);
      ushort4 o;
      o.x = f2bf(v.x); o.y = f2bf(v.y); o.z = f2bf(v.z); o.w = f2bf(v.w);
      *(ushort4*)&tile[row * 72 + col] = o;
    }
  }
  __syncthreads();
  {
    int kcol = (t & 7) * 8;
#pragma unroll
    for (int it = 0; it < 2; ++it) {
      int nrow = (t >> 3) + it * 32;
      alignas(16) unsigned short tmp[8];
#pragma unroll
      for (int j = 0; j < 8; ++j) tmp[j] = tile[(kcol + j) * 72 + nrow];
      *(uint4*)(out + (size_t)(n0 + nrow) * K + k0 + kcol) = *(const uint4*)tmp;
    }
  }
}

// ---------------- GEMM v5: m201-style 4-phase/K-tile schedule, R5 zero-conflict layout ----
// BM = AG*64, BN = BG*64; 8 waves (2M x 4N); per-wave (AG*32) x (BG*16); BK=64.
// LDS [2][BM*64] + [2][BN*64] bf16, rows of 128B, col ^= ((row&7)<<4) swizzle realized
// via pre-swizzled GLOBAL source + linear LDS dest (rule #21); reads use swizzled col.
// Phase = {pre-work (ds_reads; phase0 also: stage ALL of tile t+1 (AG+BG calls) + vmcnt(AG+BG))}
//         -> barrier -> lgkmcnt(0) -> setprio(1) + MFMA + setprio(0) -> barrier.
// vmcnt lead = 4 phases; never drains to 0 in the main loop.

#define G5_STAGE(bufi, ttile)                                                    \
  _Pragma("unroll") for (int c = 0; c < kAG; ++c)                                \
    gload_lds16((const unsigned short*)(srcA[c] + (ttile) * 128),                \
                &Asl[bufi][ldsO[c]]);                                            \
  _Pragma("unroll") for (int c = 0; c < kBG; ++c)                                \
    gload_lds16((const unsigned short*)(srcB[c] + (ttile) * 128),                \
                &Bsl[bufi][ldsO[c]]);

#define G5_READ_A(bufc, MH, KS)                                                  \
  _Pragma("unroll") for (int m = 0; m < kAG; ++m)                                \
    avreg[m] = *(const bf16x8*)((const char*)&Asl[bufc][0] + arow +              \
                                ((MH) * kAG * 16 + m * 16) * 128 + colk[KS]);
#define G5_READ_B(bufc, KS)                                                      \
  _Pragma("unroll") for (int n = 0; n < kBG; ++n)                                \
    bvreg[n] = *(const bf16x8*)((const char*)&Bsl[bufc][0] + brow +              \
                                n * 16 * 128 + colk[KS]);
#define G5_MFMA(MH)                                                              \
  __builtin_amdgcn_s_setprio(1);                                                 \
  _Pragma("unroll") for (int n = 0; n < kBG; ++n)                                \
    _Pragma("unroll") for (int m = 0; m < kAG; ++m)                              \
      acc[(MH) * kAG + m][n] = mfma_bf16(avreg[m], bvreg[n], acc[(MH)*kAG+m][n]);\
  __builtin_amdgcn_s_setprio(0);

#define GEMM5_CORE(A_, Bt_, NBN_, AG_, BG_, NST_)                                \
  __shared__ unsigned short Asl[2][(AG_) * 64 * 64];                             \
  __shared__ unsigned short Bsl[2][(BG_) * 64 * 64];                             \
  enum { kAG = (AG_), kBG = (BG_) };                                             \
  const int tid = threadIdx.x;                                                   \
  const int l = tid & 63, w = tid >> 6;                                          \
  const int wr = w >> 2, wc = w & 3;                                             \
  const int g = l >> 4, fr = l & 15;                                             \
  const int nwg = (MROWS / (kAG * 64)) * (NBN_);                                 \
  int bid = blockIdx.x;                                                          \
  int swzb = (bid & 7) * (nwg >> 3) + (bid >> 3); /* bijective: nwg%8==0 */      \
  const int n0 = (swzb % (NBN_)) * (kBG * 64);                                   \
  const int m0 = (swzb / (NBN_)) * (kAG * 64);                                   \
  f32x4 acc[2 * kAG][kBG];                                                       \
  _Pragma("unroll") for (int i = 0; i < 2 * kAG; ++i)                            \
    _Pragma("unroll") for (int j = 0; j < kBG; ++j)                              \
      _Pragma("unroll") for (int r = 0; r < 4; ++r) acc[i][j][r] = 0.0f;         \
  /* staging geometry: chunk c = 64 rows; lane covers row c*64+(tid>>3),         \
     source col pre-XORed so LDS[row][col^((row&7)<<4)] = G[row][col]. */        \
  int ldsO[(kAG > kBG ? kAG : kBG)];                                             \
  const char* srcA[kAG];                                                         \
  const char* srcB[kBG];                                                         \
  {                                                                              \
    const int rr = tid >> 3;                                                     \
    const int cs = ((tid & 7) * 16) ^ ((rr & 7) << 4);                           \
    _Pragma("unroll") for (int c = 0; c < (kAG > kBG ? kAG : kBG); ++c)          \
      ldsO[c] = (c * 8192 + tid * 16) >> 1;                                      \
    _Pragma("unroll") for (int c = 0; c < kAG; ++c)                              \
      srcA[c] = (const char*)(A_) + (size_t)(m0 + c * 64 + rr) * 2048 + cs;      \
    _Pragma("unroll") for (int c = 0; c < kBG; ++c)                              \
      srcB[c] = (const char*)(Bt_) + (size_t)(n0 + c * 64 + rr) * 2048 + cs;     \
  }                                                                              \
  const int arow = (wr * (kAG * 32) + fr) * 128;                                 \
  const int brow = (wc * (kBG * 16) + fr) * 128;                                 \
  int colk[2];                                                                   \
  colk[0] = (g * 16) ^ ((fr & 7) << 4);                                          \
  colk[1] = (64 + g * 16) ^ ((fr & 7) << 4);                                     \
  bf16x8 avreg[kAG], bvreg[kBG];                                                 \
  /* prologue: tile 0 -> buf0, tile 1 -> buf1 */                                 \
  G5_STAGE(0, 0)                                                                 \
  G5_STAGE(1, 1)                                                                 \
  for (int t = 0; t < 16; ++t) {                                                 \
    const int cur = t & 1;                                                       \
    /* ---- phase 0 ---- */                                                      \
    if (t < 15) { G5_STAGE(cur ^ 1, t + 1) VMC(NST_); } else { VMC(0); }         \
    DSB; BARRIER; DSB;                                                           \
    G5_READ_A(cur, 0, 0) G5_READ_B(cur, 0)                                       \
    LGKM0; G5_MFMA(0) DSB; BARRIER; DSB;                                         \
    /* ---- phase 1 ---- */                                                      \
    G5_READ_A(cur, 1, 0)                                                         \
    DSB; BARRIER; DSB;                                                           \
    LGKM0; G5_MFMA(1) DSB; BARRIER; DSB;                                         \
    /* ---- phase 2 ---- */                                                      \
    G5_READ_A(cur, 0, 1) G5_READ_B(cur, 1)                                       \
    DSB; BARRIER; DSB;                                                           \
    LGKM0; G5_MFMA(0) DSB; BARRIER; DSB;                                         \
    /* ---- phase 3 ---- */                                                      \
    G5_READ_A(cur, 1, 1)                                                         \
    DSB; BARRIER; DSB;                                                           \
    LGKM0; G5_MFMA(1) DSB; BARRIER; DSB;                                         \
  }

// QKV GEMM: 256x192 tile (AG=4, BG=3), grid 32x16 = 512 = 2 exact rounds.
__global__ __launch_bounds__(512) void gemm_qkv(
    const unsigned short* __restrict__ A, const unsigned short* __restrict__ Bt,
    const float* __restrict__ bias,
    unsigned short* __restrict__ Qo, unsigned short* __restrict__ Ko,
    unsigned short* __restrict__ VTo) {
  GEMM5_CORE(A, Bt, 16, 4, 3, 7)
#pragma unroll
  for (int i = 0; i < 8; ++i) {
    int mb = m0 + wr * 128 + i * 16 + 4 * g;
    int bidx = mb >> 10;
    int t = mb & 1023;
#pragma unroll
    for (int j = 0; j < 3; ++j) {
      int n = n0 + wc * 48 + j * 16 + fr;
      float bv2 = bias[n];
      int part = n >> 10;
      int nn2 = n & 1023;
      int h = nn2 >> 6, d = nn2 & 63;
      if (part == 2) {
        alignas(8) unsigned short pk[4];
#pragma unroll
        for (int r = 0; r < 4; ++r) pk[r] = f2bf(acc[i][j][r] + bv2);
        *(ushort4*)&VTo[((size_t)(bidx * NHEAD + h) * HDIM + d) * SEQ + t] =
            *(const ushort4*)pk;
      } else {
        unsigned short* dst = (part == 0) ? Qo : Ko;
        float scl = (part == 0) ? 0.125f : 1.0f;   // fold 1/sqrt(hd) into Q
        size_t base = ((size_t)(bidx * NHEAD + h) * SEQ + t) * HDIM + d;
#pragma unroll
        for (int r = 0; r < 4; ++r)
          dst[base + (size_t)r * HDIM] = f2bf((acc[i][j][r] + bv2) * scl);
      }
    }
  }
}

// Proj GEMM: 128x256 tile (AG=2, BG=4), grid 64x4 = 256 = 1 exact round. f32 out.
__global__ __launch_bounds__(512) void gemm_proj(
    const unsigned short* __restrict__ A, const unsigned short* __restrict__ Bt,
    const float* __restrict__ bias, float* __restrict__ Out) {
  GEMM5_CORE(A, Bt, 4, 2, 4, 6)
#pragma unroll
  for (int i = 0; i < 4; ++i) {
    int mb = m0 + wr * 64 + i * 16 + 4 * g;
#pragma unroll
    for (int j = 0; j < 4; ++j) {
      int n = n0 + wc * 64 + j * 16 + fr;
      float bv2 = bias[n];
#pragma unroll
      for (int r = 0; r < 4; ++r)
        Out[(size_t)(mb + r) * N_EMBD + n] = acc[i][j][r] + bv2;
    }
  }
}

// ---------------- flash-style causal attention (unchanged from R5) ----------------
__global__ __launch_bounds__(256) void attn_kernel(
    const unsigned short* __restrict__ Q, const unsigned short* __restrict__ Kv,
    const unsigned short* __restrict__ VT, unsigned short* __restrict__ Y) {
  __shared__ unsigned short Kt[2][4096];
  __shared__ unsigned short Vt[2][4096];
  __shared__ unsigned short p_lds[4 * 32 * 72];
  __shared__ float smx[4][32];
  int tid = threadIdx.x, l = tid & 63, w = tid >> 6;
  int orig = blockIdx.x;
  int swz = (orig & 7) * 128 + (orig >> 3);
  int bh = swz >> 3;
  int qi = 7 - (swz & 7);
  int b = bh >> 4, h = bh & 15;
  int q0 = qi * 128;
  int wq = q0 + w * 32;
  const unsigned short* Qb = Q + (size_t)bh * SEQ * HDIM;
  const char* Kc = (const char*)(Kv + (size_t)bh * SEQ * HDIM);
  const char* Vc = (const char*)(VT + (size_t)bh * HDIM * SEQ);
  unsigned short* pw = &p_lds[w * 32 * 72];
  const int g = l >> 4;
  const int fr = l & 15;

  const int P0 = tid * 16, P1 = tid * 16 + 4096;
  const int r0 = P0 >> 7, r1 = P1 >> 7;
  const int s0 = (P0 & 127) ^ ((r0 & 7) << 4);
  const int s1 = (P1 & 127) ^ ((r1 & 7) << 4);
  const char* Kg0 = Kc + r0 * 128 + s0;
  const char* Kg1 = Kc + r1 * 128 + s1;
  const char* Vg0 = Vc + (size_t)r0 * 2048 + s0;
  const char* Vg1 = Vc + (size_t)r1 * 2048 + s1;

  const int bc = (16 * g) ^ ((l & 7) << 4);

  bf16x8 aq[2][2];
#pragma unroll
  for (int i = 0; i < 2; ++i)
#pragma unroll
    for (int ik = 0; ik < 2; ++ik)
      aq[i][ik] = *(const bf16x8*)&Qb[(size_t)(wq + i * 16 + fr) * HDIM + ik * 32 + 8 * g];

  float mrun[2], lpart[2];
  mrun[0] = mrun[1] = -3.0e38f;
  lpart[0] = lpart[1] = 0.0f;
  f32x4 acc_o[2][4];
#pragma unroll
  for (int i = 0; i < 2; ++i)
#pragma unroll
    for (int jd = 0; jd < 4; ++jd)
#pragma unroll
      for (int r = 0; r < 4; ++r) acc_o[i][jd][r] = 0.0f;

  const int n_it = (q0 + 128) >> 6;

  gload_lds16((const unsigned short*)(Kg0), &Kt[0][P0 >> 1]);
  gload_lds16((const unsigned short*)(Kg1), &Kt[0][P1 >> 1]);
  gload_lds16((const unsigned short*)(Vg0), &Vt[0][P0 >> 1]);
  gload_lds16((const unsigned short*)(Vg1), &Vt[0][P1 >> 1]);

  for (int it = 0; it < n_it; ++it) {
    const int kv0 = it << 6;
    const int cur = it & 1;
    if (it + 1 < n_it) {
      const int nx = kv0 + 64;
      gload_lds16((const unsigned short*)(Kg0 + nx * 128), &Kt[cur ^ 1][P0 >> 1]);
      gload_lds16((const unsigned short*)(Kg1 + nx * 128), &Kt[cur ^ 1][P1 >> 1]);
      gload_lds16((const unsigned short*)(Vg0 + nx * 2),   &Vt[cur ^ 1][P0 >> 1]);
      gload_lds16((const unsigned short*)(Vg1 + nx * 2),   &Vt[cur ^ 1][P1 >> 1]);
      asm volatile("s_waitcnt vmcnt(4)" ::: "memory");
    } else {
      asm volatile("s_waitcnt vmcnt(0)" ::: "memory");
    }
    __builtin_amdgcn_sched_barrier(0);
    __builtin_amdgcn_s_barrier();
    __builtin_amdgcn_sched_barrier(0);

    const char* Kbuf = (const char*)Kt[cur];
    const char* Vbuf = (const char*)Vt[cur];

    f32x4 s2[2][4];
#pragma unroll
    for (int i = 0; i < 2; ++i)
#pragma unroll
      for (int j = 0; j < 4; ++j)
#pragma unroll
        for (int r = 0; r < 4; ++r) s2[i][j][r] = 0.0f;

    __builtin_amdgcn_s_setprio(1);
#pragma unroll
    for (int ik = 0; ik < 2; ++ik) {
#pragma unroll
      for (int j = 0; j < 4; ++j) {
        bf16x8 bk = *(const bf16x8*)(Kbuf + (j * 16 + fr) * 128 + (bc ^ (ik << 6)));
#pragma unroll
        for (int i = 0; i < 2; ++i) s2[i][j] = mfma_bf16(bk, aq[i][ik], s2[i][j]);
      }
    }
    __builtin_amdgcn_s_setprio(0);

    bool need_mask = (kv0 + 63) > wq;
    if (need_mask) {
#pragma unroll
      for (int i = 0; i < 2; ++i) {
        int q = wq + i * 16 + fr;
#pragma unroll
        for (int j = 0; j < 4; ++j)
#pragma unroll
          for (int r = 0; r < 4; ++r) {
            int kv = kv0 + j * 16 + 4 * g + r;
            if (kv > q) s2[i][j][r] = -3.0e38f;
          }
      }
    }

    float pm[2];
#pragma unroll
    for (int i = 0; i < 2; ++i) {
      float m01 = fmaxf(fmaxf(s2[i][0][0], s2[i][0][1]), fmaxf(s2[i][0][2], s2[i][0][3]));
      float m11 = fmaxf(fmaxf(s2[i][1][0], s2[i][1][1]), fmaxf(s2[i][1][2], s2[i][1][3]));
      float m21 = fmaxf(fmaxf(s2[i][2][0], s2[i][2][1]), fmaxf(s2[i][2][2], s2[i][2][3]));
      float m31 = fmaxf(fmaxf(s2[i][3][0], s2[i][3][1]), fmaxf(s2[i][3][2], s2[i][3][3]));
      float mm = fmaxf(fmaxf(m01, m11), fmaxf(m21, m31));
      mm = fmaxf(mm, __shfl_xor(mm, 16, 64));
      mm = fmaxf(mm, __shfl_xor(mm, 32, 64));
      pm[i] = mm;
    }

    bool okl = (pm[0] <= mrun[0] + 8.0f) && (pm[1] <= mrun[1] + 8.0f);
    if (!__all(okl)) {
#pragma unroll
      for (int i = 0; i < 2; ++i) {
        float mn = fmaxf(mrun[i], pm[i]);
        float sc = __expf(mrun[i] - mn);
        mrun[i] = mn;
        lpart[i] *= sc;
        if (g == 0) smx[w][i * 16 + fr] = sc;
      }
      asm volatile("s_waitcnt lgkmcnt(0)" ::: "memory");
#pragma unroll
      for (int i = 0; i < 2; ++i)
#pragma unroll
        for (int r = 0; r < 4; ++r) {
          float sc = smx[w][i * 16 + 4 * g + r];
#pragma unroll
          for (int jd = 0; jd < 4; ++jd) acc_o[i][jd][r] *= sc;
        }
    }

#pragma unroll
    for (int i = 0; i < 2; ++i) {
#pragma unroll
      for (int j = 0; j < 4; ++j) {
        float p0 = __expf(s2[i][j][0] - mrun[i]);
        float p1 = __expf(s2[i][j][1] - mrun[i]);
        float p2 = __expf(s2[i][j][2] - mrun[i]);
        float p3 = __expf(s2[i][j][3] - mrun[i]);
        lpart[i] += (p0 + p1) + (p2 + p3);
        ushort4 pk;
        pk.x = f2bf(p0); pk.y = f2bf(p1); pk.z = f2bf(p2); pk.w = f2bf(p3);
        *(ushort4*)&pw[(i * 16 + fr) * 72 + j * 16 + 4 * g] = pk;
      }
    }

    __builtin_amdgcn_s_setprio(1);
#pragma unroll
    for (int ik2 = 0; ik2 < 2; ++ik2) {
      bf16x8 ap[2];
#pragma unroll
      for (int i = 0; i < 2; ++i)
        ap[i] = *(const bf16x8*)&pw[(i * 16 + fr) * 72 + ik2 * 32 + 8 * g];
#pragma unroll
      for (int jd = 0; jd < 4; ++jd) {
        bf16x8 bv = *(const bf16x8*)(Vbuf + (jd * 16 + fr) * 128 + (bc ^ (ik2 << 6)));
#pragma unroll
        for (int i = 0; i < 2; ++i) acc_o[i][jd] = mfma_bf16(ap[i], bv, acc_o[i][jd]);
      }
    }
    __builtin_amdgcn_s_setprio(0);

    asm volatile("s_waitcnt lgkmcnt(0)" ::: "memory");
    __builtin_amdgcn_sched_barrier(0);
    __builtin_amdgcn_s_barrier();
    __builtin_amdgcn_sched_barrier(0);
  }

#pragma unroll
  for (int i = 0; i < 2; ++i) {
    float t = lpart[i];
    t += __shfl_xor(t, 16, 64);
    t += __shfl_xor(t, 32, 64);
    if (g == 0) smx[w][i * 16 + fr] = t;
  }
  asm volatile("s_waitcnt lgkmcnt(0)" ::: "memory");
#pragma unroll
  for (int i = 0; i < 2; ++i)
#pragma unroll
    for (int r = 0; r < 4; ++r) {
      float inv = 1.0f / smx[w][i * 16 + 4 * g + r];
      int q = wq + i * 16 + 4 * g + r;
#pragma unroll
      for (int jd = 0; jd < 4; ++jd)
        Y[((size_t)b * SEQ + q) * N_EMBD + h * HDIM + jd * 16 + fr] =
            f2bf(acc_o[i][jd][r] * inv);
    }
}

// ---------------- launcher ----------------
extern "C" void kernel_launch(void* const* d_in, const int* in_sizes, int n_in,
                              void* d_out, int out_size, void* d_ws, size_t ws_size,
                              hipStream_t stream) {
  (void)in_sizes; (void)n_in; (void)out_size; (void)ws_size;
  const float* x      = (const float*)d_in[0];
  const float* w_attn = (const float*)d_in[1];
  const float* b_attn = (const float*)d_in[2];
  const float* w_proj = (const float*)d_in[3];
  const float* b_proj = (const float*)d_in[4];
  float* out = (float*)d_out;

  char* ws = (char*)d_ws;
  size_t off = 0;
  auto carve = [&](size_t bytes) -> char* {
    char* p = ws + off;
    off += (bytes + 255) & ~(size_t)255;
    return p;
  };
  unsigned short* xb     = (unsigned short*)carve((size_t)MROWS * N_EMBD * 2);
  unsigned short* wTattn = (unsigned short*)carve((size_t)3 * N_EMBD * N_EMBD * 2);
  unsigned short* wTproj = (unsigned short*)carve((size_t)N_EMBD * N_EMBD * 2);
  unsigned short* Qb     = (unsigned short*)carve((size_t)MROWS * N_EMBD * 2);
  unsigned short* Kb     = (unsigned short*)carve((size_t)MROWS * N_EMBD * 2);
  unsigned short* VTb    = (unsigned short*)carve((size_t)MROWS * N_EMBD * 2);
  unsigned short* Yb     = (unsigned short*)carve((size_t)MROWS * N_EMBD * 2);
  carve(4096);

  cast_f32_bf16<<<dim3(MROWS * N_EMBD / 1024), 256, 0, stream>>>(x, xb, MROWS * N_EMBD);
  transpose_cast<<<dim3(3 * N_EMBD / 64, N_EMBD / 64), 256, 0, stream>>>(w_attn, wTattn, N_EMBD, 3 * N_EMBD);
  transpose_cast<<<dim3(N_EMBD / 64, N_EMBD / 64), 256, 0, stream>>>(w_proj, wTproj, N_EMBD, N_EMBD);
  gemm_qkv<<<dim3(512), 512, 0, stream>>>(xb, wTattn, b_attn, Qb, Kb, VTb);
  attn_kernel<<<dim3(BATCH * NHEAD * (SEQ / 128)), 256, 0, stream>>>(Qb, Kb, VTb, Yb);
  gemm_proj<<<dim3(256), 512, 0, stream>>>(Yb, wTproj, b_proj, out);
}

// Round 9
// 182.312 us; speedup vs baseline: 1.0866x; 1.0553x over previous
//
#include <hip/hip_runtime.h>
#include <stdint.h>

#define N_EMBD 1024
#define NHEAD  16
#define HDIM   64
#define BATCH  8
#define SEQ    1024
#define MROWS  (BATCH*SEQ)   // 8192

typedef __bf16 bf16x8 __attribute__((ext_vector_type(8)));
typedef float  f32x4  __attribute__((ext_vector_type(4)));

__device__ inline unsigned short f2bf(float f) {
  uint32_t u = __float_as_uint(f);
  u += 0x7FFFu + ((u >> 16) & 1u);   // RNE; inputs are finite
  return (unsigned short)(u >> 16);
}

__device__ inline f32x4 mfma_bf16(bf16x8 a, bf16x8 b, f32x4 c) {
  return __builtin_amdgcn_mfma_f32_16x16x32_bf16(a, b, c, 0, 0, 0);
}

__device__ inline void gload_lds16(const unsigned short* g, unsigned short* l) {
  __builtin_amdgcn_global_load_lds(
      (const __attribute__((address_space(1))) void*)g,
      (__attribute__((address_space(3))) void*)l,
      16, 0, 0);
}

// ---------------- cast f32 -> bf16 (vectorized) ----------------
__global__ __launch_bounds__(256) void cast_f32_bf16(
    const float* __restrict__ in, unsigned short* __restrict__ out, int n) {
  int i = (blockIdx.x * 256 + threadIdx.x) * 4;
  if (i >= n) return;
  float4 v = *(const float4*)(in + i);
  ushort4 o;
  o.x = f2bf(v.x); o.y = f2bf(v.y); o.z = f2bf(v.z); o.w = f2bf(v.w);
  *(ushort4*)(out + i) = o;
}

// ---------------- transpose + cast: in [K][N] f32 -> out [N][K] bf16 ----------------
__global__ __launch_bounds__(256) void transpose_cast(
    const float* __restrict__ in, unsigned short* __restrict__ out, int K, int N) {
  __shared__ unsigned short tile[64 * 72];
  int k0 = blockIdx.y * 64, n0 = blockIdx.x * 64;
  int t = threadIdx.x;
  {
    int col = (t & 15) * 4;
#pragma unroll
    for (int it = 0; it < 4; ++it) {
      int row = (t >> 4) + it * 16;
      float4 v = *(const float4*)(in + (size_t)(k0 + row) * N + n0 + col);
      ushort4 o;
      o.x = f2bf(v.x); o.y = f2bf(v.y); o.z = f2bf(v.z); o.w = f2bf(v.w);
      *(ushort4*)&tile[row * 72 + col] = o;
    }
  }
  __syncthreads();
  {
    int kcol = (t & 7) * 8;
#pragma unroll
    for (int it = 0; it < 2; ++it) {
      int nrow = (t >> 3) + it * 32;
      alignas(16) unsigned short tmp[8];
#pragma unroll
      for (int j = 0; j < 8; ++j) tmp[j] = tile[(kcol + j) * 72 + nrow];
      *(uint4*)(out + (size_t)(n0 + nrow) * K + k0 + kcol) = *(const uint4*)tmp;
    }
  }
}

// ---------------- GEMM v6: m97 structure (multi-block overlap) + zero-conflict swizzle ----
// 128x128 tile, BK=64, 4 waves (2x2), per-wave 64x64 = acc[4][4]. Single 32KB LDS buffer,
// plain __syncthreads() loop — cross-BLOCK wave overlap (≈4 blocks/CU) hides the drain
// (m114/m97 mechanism). LDS rows 128B; col ^= ((row&7)<<4) swizzle via pre-swizzled
// global source + linear dest (rule #21); fragment reads use the same XOR (R5-verified 0 conflicts).

#define GEMM97_CORE(A_, Bt_, NBN_)                                              \
  __shared__ unsigned short Asl[128 * 64];                                      \
  __shared__ unsigned short Bsl[128 * 64];                                      \
  const int tid = threadIdx.x;                                                  \
  const int l = tid & 63, w = tid >> 6;                                         \
  const int wr = w >> 1, wc = w & 1;                                            \
  const int g = l >> 4, fr = l & 15;                                            \
  const int nwg = 64 * (NBN_);                                                  \
  int bid = blockIdx.x;                                                         \
  int swzb = (bid & 7) * (nwg >> 3) + (bid >> 3); /* bijective: nwg%8==0 */     \
  const int n0 = (swzb % (NBN_)) * 128;                                         \
  const int m0 = (swzb / (NBN_)) * 128;                                         \
  f32x4 acc[4][4];                                                              \
  _Pragma("unroll") for (int i = 0; i < 4; ++i)                                 \
    _Pragma("unroll") for (int j = 0; j < 4; ++j)                               \
      _Pragma("unroll") for (int r = 0; r < 4; ++r) acc[i][j][r] = 0.0f;        \
  /* staging: call c covers tile rows c*32..c*32+31 (32 rows x 128B = 4KB). */  \
  const int rr = tid >> 3;                                                      \
  const int cs = ((tid & 7) * 16) ^ ((rr & 7) << 4);                            \
  const char* srcA[4]; const char* srcB[4];                                     \
  _Pragma("unroll") for (int c = 0; c < 4; ++c) {                               \
    srcA[c] = (const char*)(A_) + (size_t)(m0 + c * 32 + rr) * 2048 + cs;       \
    srcB[c] = (const char*)(Bt_) + (size_t)(n0 + c * 32 + rr) * 2048 + cs;      \
  }                                                                             \
  const int ldso = tid * 8;  /* shorts */                                       \
  const int arow = (wr * 64 + fr) * 128;                                        \
  const int brow = (wc * 64 + fr) * 128;                                        \
  int colk[2];                                                                  \
  colk[0] = (g * 16) ^ ((fr & 7) << 4);                                         \
  colk[1] = (64 + g * 16) ^ ((fr & 7) << 4);                                    \
  for (int kt = 0; kt < 16; ++kt) {                                             \
    __syncthreads();  /* all waves done reading previous tile */                \
    _Pragma("unroll") for (int c = 0; c < 4; ++c)                               \
      gload_lds16((const unsigned short*)(srcA[c] + kt * 128),                  \
                  &Asl[ldso + c * 2048]);                                       \
    _Pragma("unroll") for (int c = 0; c < 4; ++c)                               \
      gload_lds16((const unsigned short*)(srcB[c] + kt * 128),                  \
                  &Bsl[ldso + c * 2048]);                                       \
    __syncthreads();  /* compiler drains vmcnt before barrier: tile visible */  \
    _Pragma("unroll") for (int ks = 0; ks < 2; ++ks) {                          \
      bf16x8 av[4], bv[4];                                                      \
      _Pragma("unroll") for (int m = 0; m < 4; ++m)                             \
        av[m] = *(const bf16x8*)((const char*)Asl + arow + m * 16 * 128 +       \
                                 colk[ks]);                                     \
      _Pragma("unroll") for (int n = 0; n < 4; ++n)                             \
        bv[n] = *(const bf16x8*)((const char*)Bsl + brow + n * 16 * 128 +       \
                                 colk[ks]);                                     \
      _Pragma("unroll") for (int n = 0; n < 4; ++n)                             \
        _Pragma("unroll") for (int m = 0; m < 4; ++m)                           \
          acc[m][n] = mfma_bf16(av[m], bv[n], acc[m][n]);                       \
    }                                                                           \
  }

// QKV GEMM: grid 64x24 = 1536 blocks. Scatters Q(1/8)/K [BH][T][64] and VT [BH][64][T].
__global__ __launch_bounds__(256) void gemm_qkv(
    const unsigned short* __restrict__ A, const unsigned short* __restrict__ Bt,
    const float* __restrict__ bias,
    unsigned short* __restrict__ Qo, unsigned short* __restrict__ Ko,
    unsigned short* __restrict__ VTo) {
  GEMM97_CORE(A, Bt, 24)
#pragma unroll
  for (int i = 0; i < 4; ++i) {
    int mb = m0 + wr * 64 + i * 16 + 4 * g;
    int bidx = mb >> 10;
    int t = mb & 1023;
#pragma unroll
    for (int j = 0; j < 4; ++j) {
      int n = n0 + wc * 64 + j * 16 + fr;
      float bv2 = bias[n];
      int part = n >> 10;
      int nn2 = n & 1023;
      int h = nn2 >> 6, d = nn2 & 63;
      if (part == 2) {
        alignas(8) unsigned short pk[4];
#pragma unroll
        for (int r = 0; r < 4; ++r) pk[r] = f2bf(acc[i][j][r] + bv2);
        *(ushort4*)&VTo[((size_t)(bidx * NHEAD + h) * HDIM + d) * SEQ + t] =
            *(const ushort4*)pk;
      } else {
        unsigned short* dst = (part == 0) ? Qo : Ko;
        float scl = (part == 0) ? 0.125f : 1.0f;   // fold 1/sqrt(hd) into Q
        size_t base = ((size_t)(bidx * NHEAD + h) * SEQ + t) * HDIM + d;
#pragma unroll
        for (int r = 0; r < 4; ++r)
          dst[base + (size_t)r * HDIM] = f2bf((acc[i][j][r] + bv2) * scl);
      }
    }
  }
}

// Proj GEMM: grid 64x8 = 512 blocks. f32 out + bias.
__global__ __launch_bounds__(256) void gemm_proj(
    const unsigned short* __restrict__ A, const unsigned short* __restrict__ Bt,
    const float* __restrict__ bias, float* __restrict__ Out) {
  GEMM97_CORE(A, Bt, 8)
#pragma unroll
  for (int i = 0; i < 4; ++i) {
    int mb = m0 + wr * 64 + i * 16 + 4 * g;
#pragma unroll
    for (int j = 0; j < 4; ++j) {
      int n = n0 + wc * 64 + j * 16 + fr;
      float bv2 = bias[n];
#pragma unroll
      for (int r = 0; r < 4; ++r)
        Out[(size_t)(mb + r) * N_EMBD + n] = acc[i][j][r] + bv2;
    }
  }
}

// ---------------- flash-style causal attention (unchanged from R5) ----------------
__global__ __launch_bounds__(256) void attn_kernel(
    const unsigned short* __restrict__ Q, const unsigned short* __restrict__ Kv,
    const unsigned short* __restrict__ VT, unsigned short* __restrict__ Y) {
  __shared__ unsigned short Kt[2][4096];
  __shared__ unsigned short Vt[2][4096];
  __shared__ unsigned short p_lds[4 * 32 * 72];
  __shared__ float smx[4][32];
  int tid = threadIdx.x, l = tid & 63, w = tid >> 6;
  int orig = blockIdx.x;
  int swz = (orig & 7) * 128 + (orig >> 3);
  int bh = swz >> 3;
  int qi = 7 - (swz & 7);
  int b = bh >> 4, h = bh & 15;
  int q0 = qi * 128;
  int wq = q0 + w * 32;
  const unsigned short* Qb = Q + (size_t)bh * SEQ * HDIM;
  const char* Kc = (const char*)(Kv + (size_t)bh * SEQ * HDIM);
  const char* Vc = (const char*)(VT + (size_t)bh * HDIM * SEQ);
  unsigned short* pw = &p_lds[w * 32 * 72];
  const int g = l >> 4;
  const int fr = l & 15;

  const int P0 = tid * 16, P1 = tid * 16 + 4096;
  const int r0 = P0 >> 7, r1 = P1 >> 7;
  const int s0 = (P0 & 127) ^ ((r0 & 7) << 4);
  const int s1 = (P1 & 127) ^ ((r1 & 7) << 4);
  const char* Kg0 = Kc + r0 * 128 + s0;
  const char* Kg1 = Kc + r1 * 128 + s1;
  const char* Vg0 = Vc + (size_t)r0 * 2048 + s0;
  const char* Vg1 = Vc + (size_t)r1 * 2048 + s1;

  const int bc = (16 * g) ^ ((l & 7) << 4);

  bf16x8 aq[2][2];
#pragma unroll
  for (int i = 0; i < 2; ++i)
#pragma unroll
    for (int ik = 0; ik < 2; ++ik)
      aq[i][ik] = *(const bf16x8*)&Qb[(size_t)(wq + i * 16 + fr) * HDIM + ik * 32 + 8 * g];

  float mrun[2], lpart[2];
  mrun[0] = mrun[1] = -3.0e38f;
  lpart[0] = lpart[1] = 0.0f;
  f32x4 acc_o[2][4];
#pragma unroll
  for (int i = 0; i < 2; ++i)
#pragma unroll
    for (int jd = 0; jd < 4; ++jd)
#pragma unroll
      for (int r = 0; r < 4; ++r) acc_o[i][jd][r] = 0.0f;

  const int n_it = (q0 + 128) >> 6;

  gload_lds16((const unsigned short*)(Kg0), &Kt[0][P0 >> 1]);
  gload_lds16((const unsigned short*)(Kg1), &Kt[0][P1 >> 1]);
  gload_lds16((const unsigned short*)(Vg0), &Vt[0][P0 >> 1]);
  gload_lds16((const unsigned short*)(Vg1), &Vt[0][P1 >> 1]);

  for (int it = 0; it < n_it; ++it) {
    const int kv0 = it << 6;
    const int cur = it & 1;
    if (it + 1 < n_it) {
      const int nx = kv0 + 64;
      gload_lds16((const unsigned short*)(Kg0 + nx * 128), &Kt[cur ^ 1][P0 >> 1]);
      gload_lds16((const unsigned short*)(Kg1 + nx * 128), &Kt[cur ^ 1][P1 >> 1]);
      gload_lds16((const unsigned short*)(Vg0 + nx * 2),   &Vt[cur ^ 1][P0 >> 1]);
      gload_lds16((const unsigned short*)(Vg1 + nx * 2),   &Vt[cur ^ 1][P1 >> 1]);
      asm volatile("s_waitcnt vmcnt(4)" ::: "memory");
    } else {
      asm volatile("s_waitcnt vmcnt(0)" ::: "memory");
    }
    __builtin_amdgcn_sched_barrier(0);
    __builtin_amdgcn_s_barrier();
    __builtin_amdgcn_sched_barrier(0);

    const char* Kbuf = (const char*)Kt[cur];
    const char* Vbuf = (const char*)Vt[cur];

    f32x4 s2[2][4];
#pragma unroll
    for (int i = 0; i < 2; ++i)
#pragma unroll
      for (int j = 0; j < 4; ++j)
#pragma unroll
        for (int r = 0; r < 4; ++r) s2[i][j][r] = 0.0f;

    __builtin_amdgcn_s_setprio(1);
#pragma unroll
    for (int ik = 0; ik < 2; ++ik) {
#pragma unroll
      for (int j = 0; j < 4; ++j) {
        bf16x8 bk = *(const bf16x8*)(Kbuf + (j * 16 + fr) * 128 + (bc ^ (ik << 6)));
#pragma unroll
        for (int i = 0; i < 2; ++i) s2[i][j] = mfma_bf16(bk, aq[i][ik], s2[i][j]);
      }
    }
    __builtin_amdgcn_s_setprio(0);

    bool need_mask = (kv0 + 63) > wq;
    if (need_mask) {
#pragma unroll
      for (int i = 0; i < 2; ++i) {
        int q = wq + i * 16 + fr;
#pragma unroll
        for (int j = 0; j < 4; ++j)
#pragma unroll
          for (int r = 0; r < 4; ++r) {
            int kv = kv0 + j * 16 + 4 * g + r;
            if (kv > q) s2[i][j][r] = -3.0e38f;
          }
      }
    }

    float pm[2];
#pragma unroll
    for (int i = 0; i < 2; ++i) {
      float m01 = fmaxf(fmaxf(s2[i][0][0], s2[i][0][1]), fmaxf(s2[i][0][2], s2[i][0][3]));
      float m11 = fmaxf(fmaxf(s2[i][1][0], s2[i][1][1]), fmaxf(s2[i][1][2], s2[i][1][3]));
      float m21 = fmaxf(fmaxf(s2[i][2][0], s2[i][2][1]), fmaxf(s2[i][2][2], s2[i][2][3]));
      float m31 = fmaxf(fmaxf(s2[i][3][0], s2[i][3][1]), fmaxf(s2[i][3][2], s2[i][3][3]));
      float mm = fmaxf(fmaxf(m01, m11), fmaxf(m21, m31));
      mm = fmaxf(mm, __shfl_xor(mm, 16, 64));
      mm = fmaxf(mm, __shfl_xor(mm, 32, 64));
      pm[i] = mm;
    }

    bool okl = (pm[0] <= mrun[0] + 8.0f) && (pm[1] <= mrun[1] + 8.0f);
    if (!__all(okl)) {
#pragma unroll
      for (int i = 0; i < 2; ++i) {
        float mn = fmaxf(mrun[i], pm[i]);
        float sc = __expf(mrun[i] - mn);
        mrun[i] = mn;
        lpart[i] *= sc;
        if (g == 0) smx[w][i * 16 + fr] = sc;
      }
      asm volatile("s_waitcnt lgkmcnt(0)" ::: "memory");
#pragma unroll
      for (int i = 0; i < 2; ++i)
#pragma unroll
        for (int r = 0; r < 4; ++r) {
          float sc = smx[w][i * 16 + 4 * g + r];
#pragma unroll
          for (int jd = 0; jd < 4; ++jd) acc_o[i][jd][r] *= sc;
        }
    }

#pragma unroll
    for (int i = 0; i < 2; ++i) {
#pragma unroll
      for (int j = 0; j < 4; ++j) {
        float p0 = __expf(s2[i][j][0] - mrun[i]);
        float p1 = __expf(s2[i][j][1] - mrun[i]);
        float p2 = __expf(s2[i][j][2] - mrun[i]);
        float p3 = __expf(s2[i][j][3] - mrun[i]);
        lpart[i] += (p0 + p1) + (p2 + p3);
        ushort4 pk;
        pk.x = f2bf(p0); pk.y = f2bf(p1); pk.z = f2bf(p2); pk.w = f2bf(p3);
        *(ushort4*)&pw[(i * 16 + fr) * 72 + j * 16 + 4 * g] = pk;
      }
    }

    __builtin_amdgcn_s_setprio(1);
#pragma unroll
    for (int ik2 = 0; ik2 < 2; ++ik2) {
      bf16x8 ap[2];
#pragma unroll
      for (int i = 0; i < 2; ++i)
        ap[i] = *(const bf16x8*)&pw[(i * 16 + fr) * 72 + ik2 * 32 + 8 * g];
#pragma unroll
      for (int jd = 0; jd < 4; ++jd) {
        bf16x8 bv = *(const bf16x8*)(Vbuf + (jd * 16 + fr) * 128 + (bc ^ (ik2 << 6)));
#pragma unroll
        for (int i = 0; i < 2; ++i) acc_o[i][jd] = mfma_bf16(ap[i], bv, acc_o[i][jd]);
      }
    }
    __builtin_amdgcn_s_setprio(0);

    asm volatile("s_waitcnt lgkmcnt(0)" ::: "memory");
    __builtin_amdgcn_sched_barrier(0);
    __builtin_amdgcn_s_barrier();
    __builtin_amdgcn_sched_barrier(0);
  }

#pragma unroll
  for (int i = 0; i < 2; ++i) {
    float t = lpart[i];
    t += __shfl_xor(t, 16, 64);
    t += __shfl_xor(t, 32, 64);
    if (g == 0) smx[w][i * 16 + fr] = t;
  }
  asm volatile("s_waitcnt lgkmcnt(0)" ::: "memory");
#pragma unroll
  for (int i = 0; i < 2; ++i)
#pragma unroll
    for (int r = 0; r < 4; ++r) {
      float inv = 1.0f / smx[w][i * 16 + 4 * g + r];
      int q = wq + i * 16 + 4 * g + r;
#pragma unroll
      for (int jd = 0; jd < 4; ++jd)
        Y[((size_t)b * SEQ + q) * N_EMBD + h * HDIM + jd * 16 + fr] =
            f2bf(acc_o[i][jd][r] * inv);
    }
}

// ---------------- launcher ----------------
extern "C" void kernel_launch(void* const* d_in, const int* in_sizes, int n_in,
                              void* d_out, int out_size, void* d_ws, size_t ws_size,
                              hipStream_t stream) {
  (void)in_sizes; (void)n_in; (void)out_size; (void)ws_size;
  const float* x      = (const float*)d_in[0];
  const float* w_attn = (const float*)d_in[1];
  const float* b_attn = (const float*)d_in[2];
  const float* w_proj = (const float*)d_in[3];
  const float* b_proj = (const float*)d_in[4];
  float* out = (float*)d_out;

  char* ws = (char*)d_ws;
  size_t off = 0;
  auto carve = [&](size_t bytes) -> char* {
    char* p = ws + off;
    off += (bytes + 255) & ~(size_t)255;
    return p;
  };
  unsigned short* xb     = (unsigned short*)carve((size_t)MROWS * N_EMBD * 2);
  unsigned short* wTattn = (unsigned short*)carve((size_t)3 * N_EMBD * N_EMBD * 2);
  unsigned short* wTproj = (unsigned short*)carve((size_t)N_EMBD * N_EMBD * 2);
  unsigned short* Qb     = (unsigned short*)carve((size_t)MROWS * N_EMBD * 2);
  unsigned short* Kb     = (unsigned short*)carve((size_t)MROWS * N_EMBD * 2);
  unsigned short* VTb    = (unsigned short*)carve((size_t)MROWS * N_EMBD * 2);
  unsigned short* Yb     = (unsigned short*)carve((size_t)MROWS * N_EMBD * 2);
  carve(4096);

  cast_f32_bf16<<<dim3(MROWS * N_EMBD / 1024), 256, 0, stream>>>(x, xb, MROWS * N_EMBD);
  transpose_cast<<<dim3(3 * N_EMBD / 64, N_EMBD / 64), 256, 0, stream>>>(w_attn, wTattn, N_EMBD, 3 * N_EMBD);
  transpose_cast<<<dim3(N_EMBD / 64, N_EMBD / 64), 256, 0, stream>>>(w_proj, wTproj, N_EMBD, N_EMBD);
  gemm_qkv<<<dim3(64 * 24), 256, 0, stream>>>(xb, wTattn, b_attn, Qb, Kb, VTb);
  attn_kernel<<<dim3(BATCH * NHEAD * (SEQ / 128)), 256, 0, stream>>>(Qb, Kb, VTb, Yb);
  gemm_proj<<<dim3(64 * 8), 256, 0, stream>>>(Yb, wTproj, b_proj, out);
}